// Round 10
// baseline (109.748 us; speedup 1.0000x reference)
//
#include <hip/hip_runtime.h>
#include <hip/hip_bf16.h>

typedef __bf16 bf16;
typedef __bf16 bf16x8 __attribute__((ext_vector_type(8)));
typedef __bf16 bf16x4 __attribute__((ext_vector_type(4)));
typedef float  f32x4  __attribute__((ext_vector_type(4)));

#define KDIM 512
#define MDIM 64
#define TDIM 4096
#define BN   128
#define BK   64
#define NTILE (TDIM / BN)   // 32 tiles per batch
#define KITER (KDIM / BK)   // 8

// LDS byte layout
#define SA_OFF   0        // text tile  [64][64]  bf16, swizzled: 8192 B
#define SB_OFF   8192     // audio tile [128][64] bf16, swizzled: 16384 B
#define INVT_OFF 24576    // 64 floats
#define INVA_OFF 24832    // 128 floats
#define LDS_BYTES 25344   // 25.3 KB -> 3 blocks/CU fits (76 KB < 160 KB)

// ---- macros: every register-array index compile-time static (rule #20) ----

#define LOAD_TILE(PT, PA, K0) do {                                            \
    _Pragma("unroll")                                                         \
    for (int j = 0; j < 4; ++j)                                               \
        PT[j] = *reinterpret_cast<const f32x4*>(                              \
            tBase + (size_t)(j * 16 + r0) * KDIM + (K0) + c4 * 4);            \
    _Pragma("unroll")                                                         \
    for (int j = 0; j < 8; ++j)                                               \
        PA[j] = *reinterpret_cast<const f32x4*>(                              \
            aBase + (size_t)(j * 16 + r0) * KDIM + (K0) + c4 * 4);            \
} while (0)

#define STORE_TILE(PT, PA) do {                                               \
    _Pragma("unroll")                                                         \
    for (int j = 0; j < 4; ++j) {                                             \
        f32x4 v = PT[j];                                                      \
        ssT[j] += v.x * v.x + v.y * v.y + v.z * v.z + v.w * v.w;              \
        bf16x4 q = { (bf16)v.x, (bf16)v.y, (bf16)v.z, (bf16)v.w };            \
        const int row = j * 16 + r0;                                          \
        const int off = SA_OFF + row * 128 + ((c4 * 8) ^ ((row & 7) << 4));   \
        *reinterpret_cast<unsigned long long*>(lds + off) =                   \
            __builtin_bit_cast(unsigned long long, q);                        \
    }                                                                         \
    _Pragma("unroll")                                                         \
    for (int j = 0; j < 8; ++j) {                                             \
        f32x4 v = PA[j];                                                      \
        ssA[j] += v.x * v.x + v.y * v.y + v.z * v.z + v.w * v.w;              \
        bf16x4 q = { (bf16)v.x, (bf16)v.y, (bf16)v.z, (bf16)v.w };            \
        const int row = j * 16 + r0;                                          \
        const int off = SB_OFF + row * 128 + ((c4 * 8) ^ ((row & 7) << 4));   \
        *reinterpret_cast<unsigned long long*>(lds + off) =                   \
            __builtin_bit_cast(unsigned long long, q);                        \
    }                                                                         \
} while (0)

// MFMA via INTRINSIC (not opaque asm): the backend hazard recognizer sees
// real MFMA MachineInstrs and inserts mandatory wait-states under ANY
// register allocation (R8/R9 lesson: asm MFMA + tight launch_bounds
// miscompiles because spill/VALU->MFMA hazards go unguarded).
#define MFMA_PHASE() do {                                                     \
    _Pragma("unroll")                                                         \
    for (int kk = 0; kk < 2; ++kk) {                                          \
        const int kbyte = kk * 64 + kgrp * 16;                                \
        bf16x8 afrag[4], bfrag[2];                                            \
        _Pragma("unroll")                                                     \
        for (int mi = 0; mi < 4; ++mi) {                                      \
            const int row = mi * 16 + frow;                                   \
            afrag[mi] = *reinterpret_cast<const bf16x8*>(                     \
                lds + SA_OFF + row * 128 + (kbyte ^ ((row & 7) << 4)));       \
        }                                                                     \
        _Pragma("unroll")                                                     \
        for (int ni = 0; ni < 2; ++ni) {                                      \
            const int trow = wave * 32 + ni * 16 + frow;                      \
            bfrag[ni] = *reinterpret_cast<const bf16x8*>(                     \
                lds + SB_OFF + trow * 128 + (kbyte ^ ((trow & 7) << 4)));     \
        }                                                                     \
        _Pragma("unroll")                                                     \
        for (int mi = 0; mi < 4; ++mi)                                        \
            _Pragma("unroll")                                                 \
            for (int ni = 0; ni < 2; ++ni)                                    \
                acc[mi][ni] = __builtin_amdgcn_mfma_f32_16x16x32_bf16(        \
                    afrag[mi], bfrag[ni], acc[mi][ni], 0, 0, 0);              \
    }                                                                         \
} while (0)

// T4 barrier: ds-visibility wait only (no vmcnt drain), raw s_barrier.
#define RAW_BARRIER() do {                                                    \
    __builtin_amdgcn_sched_barrier(0);                                        \
    asm volatile("s_waitcnt lgkmcnt(0)" ::: "memory");                        \
    __builtin_amdgcn_s_barrier();                                             \
    __builtin_amdgcn_sched_barrier(0);                                        \
} while (0)

__global__ __launch_bounds__(256, 3)   // occupancy experiment, now hazard-safe
void expnegl2_fused_kernel(const float* __restrict__ audio,
                           const float* __restrict__ text,
                           float* __restrict__ out)
{
    __shared__ __attribute__((aligned(16))) unsigned char lds[LDS_BYTES];

    const int tid  = threadIdx.x;

    // XCD swizzle: each XCD owns 4 contiguous batches (text L2 locality)
    const int linear = blockIdx.x;
    const int cpx    = gridDim.x >> 3;
    const int wg     = (linear & 7) * cpx + (linear >> 3);
    const int b      = wg / NTILE;
    const int t0     = (wg % NTILE) * BN;

    const int c4   = tid & 15;
    const int r0   = tid >> 4;
    const int lane = tid & 63;
    const int wave = tid >> 6;

    const float* aBase = audio + ((size_t)b * TDIM + t0) * KDIM;
    const float* tBase = text  + (size_t)b * MDIM * KDIM;

    f32x4 acc[4][2];
    #pragma unroll
    for (int i = 0; i < 4; ++i)
        #pragma unroll
        for (int j = 0; j < 2; ++j)
            acc[i][j] = (f32x4){0.f, 0.f, 0.f, 0.f};

    float ssA[8], ssT[4];
    #pragma unroll
    for (int j = 0; j < 8; ++j) ssA[j] = 0.f;
    #pragma unroll
    for (int j = 0; j < 4; ++j) ssT[j] = 0.f;

    const int frow = lane & 15;
    const int kgrp = lane >> 4;

    // 2-deep register prefetch (R7's known-good schedule).
    f32x4 pT0[4], pA0[8], pT1[4], pA1[8];

    LOAD_TILE(pT0, pA0, 0);
    LOAD_TILE(pT1, pA1, BK);

    #pragma unroll
    for (int ki = 0; ki < KITER; ki += 2) {
        // ---- even sub-iter: consume set0 (tile ki), refill with ki+2 ----
        STORE_TILE(pT0, pA0);                    // counted vmcnt on set0 only
        if (ki + 2 < KITER) LOAD_TILE(pT0, pA0, (ki + 2) * BK);
        RAW_BARRIER();                           // loads stay in flight
        MFMA_PHASE();
        RAW_BARRIER();

        // ---- odd sub-iter: consume set1 (tile ki+1), refill with ki+3 ----
        STORE_TILE(pT1, pA1);
        if (ki + 3 < KITER) LOAD_TILE(pT1, pA1, (ki + 3) * BK);
        RAW_BARRIER();
        MFMA_PHASE();
        RAW_BARRIER();
    }

    // ---- reduce sum-of-squares across the 16 lanes sharing a row ----
    #pragma unroll
    for (int j = 0; j < 4; ++j) {
        float s = ssT[j];
        s += __shfl_xor(s, 1); s += __shfl_xor(s, 2);
        s += __shfl_xor(s, 4); s += __shfl_xor(s, 8);
        ssT[j] = s;
    }
    #pragma unroll
    for (int j = 0; j < 8; ++j) {
        float s = ssA[j];
        s += __shfl_xor(s, 1); s += __shfl_xor(s, 2);
        s += __shfl_xor(s, 4); s += __shfl_xor(s, 8);
        ssA[j] = s;
    }
    float* invT = reinterpret_cast<float*>(lds + INVT_OFF);
    float* invA = reinterpret_cast<float*>(lds + INVA_OFF);
    if (c4 == 0) {
        #pragma unroll
        for (int j = 0; j < 4; ++j)
            invT[j * 16 + r0] = 1.f / fmaxf(sqrtf(ssT[j]), 1e-12f);
        #pragma unroll
        for (int j = 0; j < 8; ++j)
            invA[j * 16 + r0] = 1.f / fmaxf(sqrtf(ssA[j]), 1e-12f);
    }
    __syncthreads();   // one-time full drain: harmless here

    // ---- epilogue: C/D layout col = lane&15, row = (lane>>4)*4 + j [m89] ----
    float* obase = out + (size_t)b * MDIM * TDIM + t0;
    #pragma unroll
    for (int ni = 0; ni < 2; ++ni) {
        const int cl = wave * 32 + ni * 16 + frow;
        const float iA = invA[cl];
        #pragma unroll
        for (int mi = 0; mi < 4; ++mi) {
            #pragma unroll
            for (int j = 0; j < 4; ++j) {
                const int m = mi * 16 + kgrp * 4 + j;
                const float dotn = acc[mi][ni][j] * invT[m] * iA;
                const float d2 = fmaxf(2.f - 2.f * dotn, 1e-12f);
                obase[(size_t)m * TDIM + cl] = __expf(-sqrtf(d2));
            }
        }
    }
}

extern "C" void kernel_launch(void* const* d_in, const int* in_sizes, int n_in,
                              void* d_out, int out_size, void* d_ws, size_t ws_size,
                              hipStream_t stream) {
    const float* audio = (const float*)d_in[0];
    const float* text  = (const float*)d_in[1];
    float* out = (float*)d_out;

    const int B = in_sizes[0] / (TDIM * KDIM);   // 32
    dim3 grid(B * NTILE);                        // 1024, %8==0
    expnegl2_fused_kernel<<<grid, 256, 0, stream>>>(audio, text, out);
}

// Round 11
// 89.915 us; speedup vs baseline: 1.2206x; 1.2206x over previous
//
#include <hip/hip_runtime.h>
#include <hip/hip_bf16.h>

typedef __bf16 bf16;
typedef __bf16 bf16x8 __attribute__((ext_vector_type(8)));
typedef __bf16 bf16x4 __attribute__((ext_vector_type(4)));
typedef float  f32x4  __attribute__((ext_vector_type(4)));

#define KDIM 512
#define MDIM 64
#define TDIM 4096
#define BN   128
#define BK   64
#define NTILE (TDIM / BN)   // 32 tiles per batch
#define KITER (KDIM / BK)   // 8

// LDS byte layout
#define SA_OFF   0        // text tile  [64][64]  bf16, swizzled: 8192 B
#define SB_OFF   8192     // audio tile [128][64] bf16, swizzled: 16384 B
#define INVT_OFF 24576    // 64 floats
#define INVA_OFF 24832    // 128 floats
#define LDS_BYTES 25344   // 25.3 KB -> 3 blocks/CU fits (76 KB < 160 KB)

// ---- macros: every register-array index compile-time static (rule #20) ----

#define LOAD_T(PT, K0) do {                                                   \
    _Pragma("unroll")                                                         \
    for (int j = 0; j < 4; ++j)                                               \
        PT[j] = *reinterpret_cast<const f32x4*>(                              \
            tBase + (size_t)(j * 16 + r0) * KDIM + (K0) + c4 * 4);            \
} while (0)

#define LOAD_A(PA, K0) do {                                                   \
    _Pragma("unroll")                                                         \
    for (int j = 0; j < 8; ++j)                                               \
        PA[j] = *reinterpret_cast<const f32x4*>(                              \
            aBase + (size_t)(j * 16 + r0) * KDIM + (K0) + c4 * 4);            \
} while (0)

#define STORE_TILE(PT, PA) do {                                               \
    _Pragma("unroll")                                                         \
    for (int j = 0; j < 4; ++j) {                                             \
        f32x4 v = PT[j];                                                      \
        ssT[j] += v.x * v.x + v.y * v.y + v.z * v.z + v.w * v.w;              \
        bf16x4 q = { (bf16)v.x, (bf16)v.y, (bf16)v.z, (bf16)v.w };            \
        const int row = j * 16 + r0;                                          \
        const int off = SA_OFF + row * 128 + ((c4 * 8) ^ ((row & 7) << 4));   \
        *reinterpret_cast<unsigned long long*>(lds + off) =                   \
            __builtin_bit_cast(unsigned long long, q);                        \
    }                                                                         \
    _Pragma("unroll")                                                         \
    for (int j = 0; j < 8; ++j) {                                             \
        f32x4 v = PA[j];                                                      \
        ssA[j] += v.x * v.x + v.y * v.y + v.z * v.z + v.w * v.w;              \
        bf16x4 q = { (bf16)v.x, (bf16)v.y, (bf16)v.z, (bf16)v.w };            \
        const int row = j * 16 + r0;                                          \
        const int off = SB_OFF + row * 128 + ((c4 * 8) ^ ((row & 7) << 4));   \
        *reinterpret_cast<unsigned long long*>(lds + off) =                   \
            __builtin_bit_cast(unsigned long long, q);                        \
    }                                                                         \
} while (0)

// MFMA via INTRINSIC: hazard-safe under any register allocation (R10
// confirmed correctness; R10's slowdown was spill pressure, fixed here by
// trimming real demand instead).
#define MFMA_PHASE() do {                                                     \
    _Pragma("unroll")                                                         \
    for (int kk = 0; kk < 2; ++kk) {                                          \
        const int kbyte = kk * 64 + kgrp * 16;                                \
        bf16x8 afrag[4], bfrag[2];                                            \
        _Pragma("unroll")                                                     \
        for (int mi = 0; mi < 4; ++mi) {                                      \
            const int row = mi * 16 + frow;                                   \
            afrag[mi] = *reinterpret_cast<const bf16x8*>(                     \
                lds + SA_OFF + row * 128 + (kbyte ^ ((row & 7) << 4)));       \
        }                                                                     \
        _Pragma("unroll")                                                     \
        for (int ni = 0; ni < 2; ++ni) {                                      \
            const int trow = wave * 32 + ni * 16 + frow;                      \
            bfrag[ni] = *reinterpret_cast<const bf16x8*>(                     \
                lds + SB_OFF + trow * 128 + (kbyte ^ ((trow & 7) << 4)));     \
        }                                                                     \
        _Pragma("unroll")                                                     \
        for (int mi = 0; mi < 4; ++mi)                                        \
            _Pragma("unroll")                                                 \
            for (int ni = 0; ni < 2; ++ni)                                    \
                acc[mi][ni] = __builtin_amdgcn_mfma_f32_16x16x32_bf16(        \
                    afrag[mi], bfrag[ni], acc[mi][ni], 0, 0, 0);              \
    }                                                                         \
} while (0)

// T4 barrier: ds-visibility wait only (no vmcnt drain), raw s_barrier.
#define RAW_BARRIER() do {                                                    \
    __builtin_amdgcn_sched_barrier(0);                                        \
    asm volatile("s_waitcnt lgkmcnt(0)" ::: "memory");                        \
    __builtin_amdgcn_s_barrier();                                             \
    __builtin_amdgcn_sched_barrier(0);                                        \
} while (0)

__global__ __launch_bounds__(256, 3)   // 12 waves/CU; demand trimmed to fit
void expnegl2_fused_kernel(const float* __restrict__ audio,
                           const float* __restrict__ text,
                           float* __restrict__ out)
{
    __shared__ __attribute__((aligned(16))) unsigned char lds[LDS_BYTES];

    const int tid  = threadIdx.x;

    // XCD swizzle: each XCD owns 4 contiguous batches (text L2 locality)
    const int linear = blockIdx.x;
    const int cpx    = gridDim.x >> 3;
    const int wg     = (linear & 7) * cpx + (linear >> 3);
    const int b      = wg / NTILE;
    const int t0     = (wg % NTILE) * BN;

    const int c4   = tid & 15;
    const int r0   = tid >> 4;
    const int lane = tid & 63;
    const int wave = tid >> 6;

    const float* aBase = audio + ((size_t)b * TDIM + t0) * KDIM;
    const float* tBase = text  + (size_t)b * MDIM * KDIM;

    f32x4 acc[4][2];
    #pragma unroll
    for (int i = 0; i < 4; ++i)
        #pragma unroll
        for (int j = 0; j < 2; ++j)
            acc[i][j] = (f32x4){0.f, 0.f, 0.f, 0.f};

    float ssA[8], ssT[4];
    #pragma unroll
    for (int j = 0; j < 8; ++j) ssA[j] = 0.f;
    #pragma unroll
    for (int j = 0; j < 4; ++j) ssT[j] = 0.f;

    const int frow = lane & 15;
    const int kgrp = lane >> 4;

    // Audio: 2-deep prefetch (HBM ~900cyc needs full-iter cover).
    // Text: 1-deep (L2-hot ~200-350cyc; phase distance ~1500cyc suffices).
    // Saves 16 VGPR vs R7 -> demand ~164 fits the 3-waves/EU budget (~168)
    // with NO spill (R10's failure mode).
    f32x4 pT[4], pA0[8], pA1[8];

    LOAD_T(pT, 0);
    LOAD_A(pA0, 0);
    LOAD_A(pA1, BK);

    #pragma unroll
    for (int ki = 0; ki < KITER; ki += 2) {
        // ---- even sub-iter: consume (pT, pA0) = tile ki ----
        STORE_TILE(pT, pA0);                             // counted vmcnt
        LOAD_T(pT, (ki + 1) * BK);                       // text for ki+1
        if (ki + 2 < KITER) LOAD_A(pA0, (ki + 2) * BK);  // audio for ki+2
        RAW_BARRIER();                                   // loads stay in flight
        MFMA_PHASE();
        RAW_BARRIER();

        // ---- odd sub-iter: consume (pT, pA1) = tile ki+1 ----
        STORE_TILE(pT, pA1);
        if (ki + 2 < KITER) LOAD_T(pT, (ki + 2) * BK);
        if (ki + 3 < KITER) LOAD_A(pA1, (ki + 3) * BK);
        RAW_BARRIER();
        MFMA_PHASE();
        RAW_BARRIER();
    }

    // ---- reduce sum-of-squares across the 16 lanes sharing a row ----
    #pragma unroll
    for (int j = 0; j < 4; ++j) {
        float s = ssT[j];
        s += __shfl_xor(s, 1); s += __shfl_xor(s, 2);
        s += __shfl_xor(s, 4); s += __shfl_xor(s, 8);
        ssT[j] = s;
    }
    #pragma unroll
    for (int j = 0; j < 8; ++j) {
        float s = ssA[j];
        s += __shfl_xor(s, 1); s += __shfl_xor(s, 2);
        s += __shfl_xor(s, 4); s += __shfl_xor(s, 8);
        ssA[j] = s;
    }
    float* invT = reinterpret_cast<float*>(lds + INVT_OFF);
    float* invA = reinterpret_cast<float*>(lds + INVA_OFF);
    if (c4 == 0) {
        #pragma unroll
        for (int j = 0; j < 4; ++j)
            invT[j * 16 + r0] = 1.f / fmaxf(sqrtf(ssT[j]), 1e-12f);
        #pragma unroll
        for (int j = 0; j < 8; ++j)
            invA[j * 16 + r0] = 1.f / fmaxf(sqrtf(ssA[j]), 1e-12f);
    }
    __syncthreads();   // one-time full drain: harmless here

    // ---- epilogue: C/D layout col = lane&15, row = (lane>>4)*4 + j [m89] ----
    float* obase = out + (size_t)b * MDIM * TDIM + t0;
    #pragma unroll
    for (int ni = 0; ni < 2; ++ni) {
        const int cl = wave * 32 + ni * 16 + frow;
        const float iA = invA[cl];
        #pragma unroll
        for (int mi = 0; mi < 4; ++mi) {
            #pragma unroll
            for (int j = 0; j < 4; ++j) {
                const int m = mi * 16 + kgrp * 4 + j;
                const float dotn = acc[mi][ni][j] * invT[m] * iA;
                const float d2 = fmaxf(2.f - 2.f * dotn, 1e-12f);
                obase[(size_t)m * TDIM + cl] = __expf(-sqrtf(d2));
            }
        }
    }
}

extern "C" void kernel_launch(void* const* d_in, const int* in_sizes, int n_in,
                              void* d_out, int out_size, void* d_ws, size_t ws_size,
                              hipStream_t stream) {
    const float* audio = (const float*)d_in[0];
    const float* text  = (const float*)d_in[1];
    float* out = (float*)d_out;

    const int B = in_sizes[0] / (TDIM * KDIM);   // 32
    dim3 grid(B * NTILE);                        // 1024, %8==0
    expnegl2_fused_kernel<<<grid, 256, 0, stream>>>(audio, text, out);
}

// Round 12
// 58.369 us; speedup vs baseline: 1.8802x; 1.5405x over previous
//
#include <hip/hip_runtime.h>
#include <hip/hip_bf16.h>

typedef __bf16 bf16;
typedef __bf16 bf16x8 __attribute__((ext_vector_type(8)));
typedef __bf16 bf16x4 __attribute__((ext_vector_type(4)));
typedef float  f32x4  __attribute__((ext_vector_type(4)));

#define KDIM 512
#define MDIM 64
#define TDIM 4096
#define BN   128
#define BK   64
#define NTILE (TDIM / BN)   // 32 tiles per batch
#define KITER (KDIM / BK)   // 8

// LDS byte layout
#define SA_OFF   0        // text tile  [64][64]  bf16, swizzled: 8192 B
#define SB_OFF   8192     // audio tile [128][64] bf16, swizzled: 16384 B
#define INVT_OFF 24576    // 64 floats
#define INVA_OFF 24832    // 128 floats
#define LDS_BYTES 25344

// ---- macros: every register-array index compile-time static (rule #20) ----

#define LOAD_TILE(PT, PA, K0) do {                                            \
    _Pragma("unroll")                                                         \
    for (int j = 0; j < 4; ++j)                                               \
        PT[j] = *reinterpret_cast<const f32x4*>(                              \
            tBase + (size_t)(j * 16 + r0) * KDIM + (K0) + c4 * 4);            \
    _Pragma("unroll")                                                         \
    for (int j = 0; j < 8; ++j)                                               \
        PA[j] = *reinterpret_cast<const f32x4*>(                              \
            aBase + (size_t)(j * 16 + r0) * KDIM + (K0) + c4 * 4);            \
} while (0)

#define STORE_TILE(PT, PA) do {                                               \
    _Pragma("unroll")                                                         \
    for (int j = 0; j < 4; ++j) {                                             \
        f32x4 v = PT[j];                                                      \
        ssT[j] += v.x * v.x + v.y * v.y + v.z * v.z + v.w * v.w;              \
        bf16x4 q = { (bf16)v.x, (bf16)v.y, (bf16)v.z, (bf16)v.w };            \
        const int row = j * 16 + r0;                                          \
        const int off = SA_OFF + row * 128 + ((c4 * 8) ^ ((row & 7) << 4));   \
        *reinterpret_cast<unsigned long long*>(lds + off) =                   \
            __builtin_bit_cast(unsigned long long, q);                        \
    }                                                                         \
    _Pragma("unroll")                                                         \
    for (int j = 0; j < 8; ++j) {                                             \
        f32x4 v = PA[j];                                                      \
        ssA[j] += v.x * v.x + v.y * v.y + v.z * v.z + v.w * v.w;              \
        bf16x4 q = { (bf16)v.x, (bf16)v.y, (bf16)v.z, (bf16)v.w };            \
        const int row = j * 16 + r0;                                          \
        const int off = SB_OFF + row * 128 + ((c4 * 8) ^ ((row & 7) << 4));   \
        *reinterpret_cast<unsigned long long*>(lds + off) =                   \
            __builtin_bit_cast(unsigned long long, q);                        \
    }                                                                         \
} while (0)

// MFMA via INTRINSIC: visible to the backend hazard recognizer -> correct
// wait-states under any allocation (R4/R8/R9 lesson: opaque-asm MFMA is
// only safe when the allocator happens to cooperate). No s_nop needed.
#define MFMA_PHASE() do {                                                     \
    _Pragma("unroll")                                                         \
    for (int kk = 0; kk < 2; ++kk) {                                          \
        const int kbyte = kk * 64 + kgrp * 16;                                \
        bf16x8 afrag[4], bfrag[2];                                            \
        _Pragma("unroll")                                                     \
        for (int mi = 0; mi < 4; ++mi) {                                      \
            const int row = mi * 16 + frow;                                   \
            afrag[mi] = *reinterpret_cast<const bf16x8*>(                     \
                lds + SA_OFF + row * 128 + (kbyte ^ ((row & 7) << 4)));       \
        }                                                                     \
        _Pragma("unroll")                                                     \
        for (int ni = 0; ni < 2; ++ni) {                                      \
            const int trow = wave * 32 + ni * 16 + frow;                      \
            bfrag[ni] = *reinterpret_cast<const bf16x8*>(                     \
                lds + SB_OFF + trow * 128 + (kbyte ^ ((trow & 7) << 4)));     \
        }                                                                     \
        _Pragma("unroll")                                                     \
        for (int mi = 0; mi < 4; ++mi)                                        \
            _Pragma("unroll")                                                 \
            for (int ni = 0; ni < 2; ++ni)                                    \
                acc[mi][ni] = __builtin_amdgcn_mfma_f32_16x16x32_bf16(        \
                    afrag[mi], bfrag[ni], acc[mi][ni], 0, 0, 0);              \
    }                                                                         \
} while (0)

// T4 barrier: ds-visibility wait only (no vmcnt drain), raw s_barrier.
// __syncthreads() would emit s_waitcnt vmcnt(0) and drain the cross-barrier
// prefetch; this keeps ~24 loads in flight across the barrier (R7: -1 µs).
#define RAW_BARRIER() do {                                                    \
    __builtin_amdgcn_sched_barrier(0);                                        \
    asm volatile("s_waitcnt lgkmcnt(0)" ::: "memory");                        \
    __builtin_amdgcn_s_barrier();                                             \
    __builtin_amdgcn_sched_barrier(0);                                        \
} while (0)

__global__ __launch_bounds__(256, 2)   // (256,3) forces ~25 VGPR spill: R10/R11
void expnegl2_fused_kernel(const float* __restrict__ audio,
                           const float* __restrict__ text,
                           float* __restrict__ out)
{
    __shared__ __attribute__((aligned(16))) unsigned char lds[LDS_BYTES];

    const int tid  = threadIdx.x;

    // XCD swizzle: each XCD owns 4 contiguous batches (text L2 locality)
    const int linear = blockIdx.x;
    const int cpx    = gridDim.x >> 3;
    const int wg     = (linear & 7) * cpx + (linear >> 3);
    const int b      = wg / NTILE;
    const int t0     = (wg % NTILE) * BN;

    const int c4   = tid & 15;
    const int r0   = tid >> 4;
    const int lane = tid & 63;
    const int wave = tid >> 6;

    const float* aBase = audio + ((size_t)b * TDIM + t0) * KDIM;
    const float* tBase = text  + (size_t)b * MDIM * KDIM;

    f32x4 acc[4][2];
    #pragma unroll
    for (int i = 0; i < 4; ++i)
        #pragma unroll
        for (int j = 0; j < 2; ++j)
            acc[i][j] = (f32x4){0.f, 0.f, 0.f, 0.f};

    float ssA[8], ssT[4];
    #pragma unroll
    for (int j = 0; j < 8; ++j) ssA[j] = 0.f;
    #pragma unroll
    for (int j = 0; j < 4; ++j) ssT[j] = 0.f;

    const int frow = lane & 15;
    const int kgrp = lane >> 4;

    // 2-deep register prefetch (R7's known-good schedule): tile k+2's loads
    // issued a full iteration ahead; counted vmcnt at the next STORE_TILE.
    f32x4 pT0[4], pA0[8], pT1[4], pA1[8];

    LOAD_TILE(pT0, pA0, 0);
    LOAD_TILE(pT1, pA1, BK);

    #pragma unroll
    for (int ki = 0; ki < KITER; ki += 2) {
        // ---- even sub-iter: consume set0 (tile ki), refill with ki+2 ----
        STORE_TILE(pT0, pA0);                    // counted vmcnt on set0 only
        if (ki + 2 < KITER) LOAD_TILE(pT0, pA0, (ki + 2) * BK);
        RAW_BARRIER();                           // loads stay in flight
        MFMA_PHASE();
        RAW_BARRIER();

        // ---- odd sub-iter: consume set1 (tile ki+1), refill with ki+3 ----
        STORE_TILE(pT1, pA1);
        if (ki + 3 < KITER) LOAD_TILE(pT1, pA1, (ki + 3) * BK);
        RAW_BARRIER();
        MFMA_PHASE();
        RAW_BARRIER();
    }

    // ---- reduce sum-of-squares across the 16 lanes sharing a row ----
    #pragma unroll
    for (int j = 0; j < 4; ++j) {
        float s = ssT[j];
        s += __shfl_xor(s, 1); s += __shfl_xor(s, 2);
        s += __shfl_xor(s, 4); s += __shfl_xor(s, 8);
        ssT[j] = s;
    }
    #pragma unroll
    for (int j = 0; j < 8; ++j) {
        float s = ssA[j];
        s += __shfl_xor(s, 1); s += __shfl_xor(s, 2);
        s += __shfl_xor(s, 4); s += __shfl_xor(s, 8);
        ssA[j] = s;
    }
    float* invT = reinterpret_cast<float*>(lds + INVT_OFF);
    float* invA = reinterpret_cast<float*>(lds + INVA_OFF);
    if (c4 == 0) {
        #pragma unroll
        for (int j = 0; j < 4; ++j)
            invT[j * 16 + r0] = 1.f / fmaxf(sqrtf(ssT[j]), 1e-12f);
        #pragma unroll
        for (int j = 0; j < 8; ++j)
            invA[j * 16 + r0] = 1.f / fmaxf(sqrtf(ssA[j]), 1e-12f);
    }
    __syncthreads();   // one-time full drain: harmless here

    // ---- epilogue: C/D layout col = lane&15, row = (lane>>4)*4 + j [m89] ----
    float* obase = out + (size_t)b * MDIM * TDIM + t0;
    #pragma unroll
    for (int ni = 0; ni < 2; ++ni) {
        const int cl = wave * 32 + ni * 16 + frow;
        const float iA = invA[cl];
        #pragma unroll
        for (int mi = 0; mi < 4; ++mi) {
            #pragma unroll
            for (int j = 0; j < 4; ++j) {
                const int m = mi * 16 + kgrp * 4 + j;
                const float dotn = acc[mi][ni][j] * invT[m] * iA;
                const float d2 = fmaxf(2.f - 2.f * dotn, 1e-12f);
                obase[(size_t)m * TDIM + cl] = __expf(-sqrtf(d2));
            }
        }
    }
}

extern "C" void kernel_launch(void* const* d_in, const int* in_sizes, int n_in,
                              void* d_out, int out_size, void* d_ws, size_t ws_size,
                              hipStream_t stream) {
    const float* audio = (const float*)d_in[0];
    const float* text  = (const float*)d_in[1];
    float* out = (float*)d_out;

    const int B = in_sizes[0] / (TDIM * KDIM);   // 32
    dim3 grid(B * NTILE);                        // 1024, %8==0
    expnegl2_fused_kernel<<<grid, 256, 0, stream>>>(audio, text, out);
}